// Round 1
// baseline (403.679 us; speedup 1.0000x reference)
//
#include <hip/hip_runtime.h>

typedef unsigned int u32;
typedef unsigned short u16;
typedef __bf16 bf16x8 __attribute__((ext_vector_type(8)));
typedef float f32x4 __attribute__((ext_vector_type(4)));

#define D 2048           // D_IN == D_MODEL == S == 2048
#define BATCH 2

// ---------- helpers ----------
__device__ __forceinline__ u32 bf16rne(float f) {
  u32 u = __builtin_bit_cast(u32, f);
  return (u + 0x7fffu + ((u >> 16) & 1u)) >> 16;
}
__device__ __forceinline__ u32 pk2(float lo, float hi) {
  return bf16rne(lo) | (bf16rne(hi) << 16);
}
__device__ __forceinline__ void async16(const u16* g, u16* l) {
  // 16B global -> LDS direct copy; LDS dest is wave-uniform base + lane*16.
  __builtin_amdgcn_global_load_lds(
      (const __attribute__((address_space(1))) void*)g,
      (__attribute__((address_space(3))) void*)l, 16, 0, 0);
}

// ---------- kernel 1: x fp32 -> bf16 (same layout, K-contiguous) ----------
__global__ void __launch_bounds__(256) prep_x_kernel(const float* __restrict__ x,
                                                     u16* __restrict__ o) {
  size_t t = (size_t)blockIdx.x * 256 + threadIdx.x;  // one uint4 (8 elems) per thread
  const float4* x4 = (const float4*)x;
  float4 a = x4[2 * t], b = x4[2 * t + 1];
  ((uint4*)o)[t] = make_uint4(pk2(a.x, a.y), pk2(a.z, a.w),
                              pk2(b.x, b.y), pk2(b.z, b.w));
}

// ---------- kernel 2: w_sel[b]^T in bf16: wt[b][n][k] = bf16(p0*W[i0][k][n] + p1*W[i1][k][n])
// Reads coalesced along n (lane = n); each thread owns one n-column for 32 k's and
// writes its 64B contiguous wt row chunk (k-contiguous) with 4x uint4 stores.
__global__ void __launch_bounds__(256) prep_w_kernel(const float* __restrict__ W,
                                                     const int* __restrict__ sidx,
                                                     const float* __restrict__ sprob,
                                                     u16* __restrict__ wt) {
  const int b = blockIdx.z;
  const int n = blockIdx.x * 256 + threadIdx.x;
  const int k0 = blockIdx.y * 32;
  const int i0 = sidx[2 * b], i1 = sidx[2 * b + 1];
  const float p0 = sprob[2 * b], p1 = sprob[2 * b + 1];
  const float* w0 = W + ((size_t)i0 * D + k0) * D + n;
  const float* w1 = W + ((size_t)i1 * D + k0) * D + n;
  u32 r[16];
#pragma unroll
  for (int kk = 0; kk < 16; ++kk) {
    float a0 = w0[(size_t)(2 * kk) * D],     c0 = w1[(size_t)(2 * kk) * D];
    float a1 = w0[(size_t)(2 * kk + 1) * D], c1 = w1[(size_t)(2 * kk + 1) * D];
    r[kk] = pk2(p0 * a0 + p1 * c0, p0 * a1 + p1 * c1);
  }
  uint4* dst = (uint4*)(wt + ((size_t)b * D + n) * D + k0);
#pragma unroll
  for (int q = 0; q < 4; ++q)
    dst[q] = make_uint4(r[4 * q], r[4 * q + 1], r[4 * q + 2], r[4 * q + 3]);
}

// ---------- kernel 3: out[b] = xb[b] @ wt[b]^T + bsel[b]  (m97 structure) ----------
// 128x128 tile, BK=32, 256 threads = 4 waves, each wave a 64x64 sub-tile as 4x4
// mfma_f32_16x16x32_bf16. Both operands K-major; staged via global_load_lds(16B).
__global__ void __launch_bounds__(256) gemm_kernel(const u16* __restrict__ xb,
                                                   const u16* __restrict__ wt,
                                                   const float* __restrict__ bias,
                                                   const int* __restrict__ sidx,
                                                   const float* __restrict__ sprob,
                                                   float* __restrict__ out) {
  __shared__ __align__(16) u16 As[128 * 32];  // As[r][k], row stride 32 bf16
  __shared__ __align__(16) u16 Bs[128 * 32];  // Bs[n][k]

  const int b  = blockIdx.z;
  const int n0 = blockIdx.x * 128;
  const int m0 = blockIdx.y * 128;
  const int t = threadIdx.x;
  const int lane = t & 63;
  const int wm = ((t >> 6) & 1) * 64;   // wave m-offset
  const int wn = ((t >> 6) >> 1) * 64;  // wave n-offset

  const u16* Ab = xb + (size_t)b * D * D;
  const u16* Bb = wt + (size_t)b * D * D;

  // staging: 16B granule e = j*256 + t; row r = e>>2, chunk c = e&3 (8 bf16)
  const int r0 = t >> 2, c8 = (t & 3) * 8;
  const u16* gA0 = Ab + (size_t)(m0 + r0) * D + c8;
  const u16* gA1 = Ab + (size_t)(m0 + 64 + r0) * D + c8;
  const u16* gB0 = Bb + (size_t)(n0 + r0) * D + c8;
  const u16* gB1 = Bb + (size_t)(n0 + 64 + r0) * D + c8;
  u16* lA0 = As + (t & ~63) * 8;          // wave-uniform LDS bases
  u16* lA1 = As + (256 + (t & ~63)) * 8;
  u16* lB0 = Bs + (t & ~63) * 8;
  u16* lB1 = Bs + (256 + (t & ~63)) * 8;

  const int fm = lane & 15;          // m (A) / n (B) index within 16-tile
  const int kh = (lane >> 4) * 8;    // k chunk within BK=32

  f32x4 acc[4][4] = {};

  for (int k0 = 0; k0 < D; k0 += 32) {
    async16(gA0 + k0, lA0);
    async16(gA1 + k0, lA1);
    async16(gB0 + k0, lB0);
    async16(gB1 + k0, lB1);
    __syncthreads();  // drains vmcnt(0): staging visible

    bf16x8 af[4], bfr[4];
#pragma unroll
    for (int i = 0; i < 4; ++i) {
      af[i]  = *(const bf16x8*)(As + (wm + i * 16 + fm) * 32 + kh);
      bfr[i] = *(const bf16x8*)(Bs + (wn + i * 16 + fm) * 32 + kh);
    }
#pragma unroll
    for (int i = 0; i < 4; ++i)
#pragma unroll
      for (int j = 0; j < 4; ++j)
        acc[i][j] = __builtin_amdgcn_mfma_f32_16x16x32_bf16(af[i], bfr[j], acc[i][j], 0, 0, 0);
    __syncthreads();  // all waves done reading before next stage
  }

  // epilogue: C/D layout col=lane&15, row=(lane>>4)*4+reg; fuse bias superposition
  const int i0 = sidx[2 * b], i1 = sidx[2 * b + 1];
  const float p0 = sprob[2 * b], p1 = sprob[2 * b + 1];
  const int rq = (lane >> 4) * 4;
  float* Ob = out + (size_t)b * D * D;
#pragma unroll
  for (int j = 0; j < 4; ++j) {
    const int colg = n0 + wn + j * 16 + fm;
    const float bsel = p0 * bias[i0 * D + colg] + p1 * bias[i1 * D + colg];
#pragma unroll
    for (int i = 0; i < 4; ++i) {
      const int rowb = m0 + wm + i * 16 + rq;
#pragma unroll
      for (int r = 0; r < 4; ++r)
        Ob[(size_t)(rowb + r) * D + colg] = acc[i][j][r] + bsel;
    }
  }
}

extern "C" void kernel_launch(void* const* d_in, const int* in_sizes, int n_in,
                              void* d_out, int out_size, void* d_ws, size_t ws_size,
                              hipStream_t stream) {
  const float* tensor = (const float*)d_in[0];   // (2,2048,16,128) fp32
  const int*   sidx   = (const int*)d_in[1];     // (2,2) int32
  const float* sprob  = (const float*)d_in[2];   // (2,2) fp32
  const float* weight = (const float*)d_in[3];   // (16,2048,2048) fp32
  const float* bias   = (const float*)d_in[4];   // (16,2048) fp32
  float* out = (float*)d_out;                    // (2,2048,2048) fp32

  u16* xb = (u16*)d_ws;                          // (2,2048,2048) bf16, 16 MB
  u16* wt = xb + (size_t)BATCH * D * D;          // (2,2048,2048) bf16, 16 MB

  hipLaunchKernelGGL(prep_x_kernel, dim3((BATCH * D * D) / (256 * 8)), dim3(256), 0, stream,
                     tensor, xb);
  hipLaunchKernelGGL(prep_w_kernel, dim3(D / 256, D / 32, BATCH), dim3(256), 0, stream,
                     weight, sidx, sprob, wt);
  hipLaunchKernelGGL(gemm_kernel, dim3(D / 128, D / 128, BATCH), dim3(256), 0, stream,
                     xb, wt, bias, sidx, sprob, out);
}